// Round 1
// baseline (862.068 us; speedup 1.0000x reference)
//
#include <hip/hip_runtime.h>
#include <math.h>

#define BB 16
#define HH 32
#define KVHH 8
#define GG 4
#define DD 128
#define SS 4096
#define PGROUPS 64              // split-S partials per (b, kvh)
#define SPAN (SS / PGROUPS)     // 64 positions per group
#define PSTRIDE (GG * DD + 2 * GG)  // 520 floats: acc[4][128], m[4], l[4]
#define SCALE 0.08838834764831845f

// Kernel 1: split-S flash-decoding partials.
// grid = B*KVH*8 blocks, block = 256 threads = 8 groups of 32 lanes.
// Each group: one (b, kvh, 64-position span); lane holds 4 d-values.
__global__ __launch_bounds__(256) void pa_split(
    const float* __restrict__ q,
    const float* __restrict__ kc,
    const float* __restrict__ vc,
    const int* __restrict__ slots,
    const int* __restrict__ positions,
    const int* __restrict__ ctxlen,
    float* __restrict__ part)
{
  const int blk  = blockIdx.x;
  const int sub  = blk & 7;
  const int bkv  = blk >> 3;
  const int b    = bkv >> 3;    // KVH = 8
  const int kvh  = bkv & 7;
  const int tid  = threadIdx.x;
  const int lane = tid & 31;
  const int grp  = tid >> 5;
  const int p    = sub * 8 + grp;   // 0..63
  const int s0   = p * SPAN;
  const int ctx  = ctxlen[b];
  int nvalid = ctx - s0;
  nvalid = nvalid < 0 ? 0 : (nvalid > SPAN ? SPAN : nvalid);

  const int d0 = lane * 4;
  // inv_freq for this lane's 4 d-values: 10000^(-j/64), j = d & 63
  float invf[4];
  #pragma unroll
  for (int i = 0; i < 4; ++i) {
    int j = (d0 + i) & 63;
    invf[i] = __expf(-0.14391156f * (float)j);   // ln(10000)/64
  }

  // ---- rope'd, pre-scaled query fragments for the 4 query heads ----
  const int pos_last = positions[b * SS + (ctx - 1)];
  float qsn[4], qcs[4];
  #pragma unroll
  for (int i = 0; i < 4; ++i) {
    __sincosf((float)pos_last * invf[i], &qsn[i], &qcs[i]);
  }
  float qr[GG][4];
  #pragma unroll
  for (int g = 0; g < GG; ++g) {
    const float4 x4 = *(const float4*)(q + ((size_t)b * HH + kvh * GG + g) * DD + d0);
    float x[4] = {x4.x, x4.y, x4.z, x4.w};
    #pragma unroll
    for (int i = 0; i < 4; ++i) {
      float px = __shfl_xor(x[i], 16, 32);       // partner element d ^ 64
      float r  = (lane < 16) ? -px : px;
      qr[g][i] = (x[i] * qcs[i] + r * qsn[i]) * SCALE;
    }
  }

  // preload slots/positions for the whole span (64 entries over 32 lanes)
  const int sbase = b * SS + s0;
  const int slotA = slots[sbase + lane];
  const int slotB = slots[sbase + 32 + lane];
  const int posA  = positions[sbase + lane];
  const int posB  = positions[sbase + 32 + lane];

  float m[GG], l[GG], acc[GG][4];
  #pragma unroll
  for (int g = 0; g < GG; ++g) {
    m[g] = -1e30f; l[g] = 0.f;
    #pragma unroll
    for (int i = 0; i < 4; ++i) acc[g][i] = 0.f;
  }

  float4 k4, v4;
  int pos_cur = 0;
  if (nvalid > 0) {
    int slot = __shfl(slotA, 0, 32);
    pos_cur  = __shfl(posA, 0, 32);
    const size_t roff = ((size_t)slot * KVHH + kvh) * DD + d0;
    k4 = *(const float4*)(kc + roff);
    v4 = *(const float4*)(vc + roff);
  }

  for (int it = 0; it < nvalid; ++it) {
    // prefetch next row while computing current
    float4 nk4 = k4, nv4 = v4;
    int pos_nxt = 0;
    if (it + 1 < nvalid) {
      const int i1 = it + 1;
      int slot = (i1 < 32) ? __shfl(slotA, i1, 32) : __shfl(slotB, i1 - 32, 32);
      pos_nxt  = (i1 < 32) ? __shfl(posA, i1, 32) : __shfl(posB, i1 - 32, 32);
      const size_t roff = ((size_t)slot * KVHH + kvh) * DD + d0;
      nk4 = *(const float4*)(kc + roff);
      nv4 = *(const float4*)(vc + roff);
    }

    // RoPE on K
    float kx[4] = {k4.x, k4.y, k4.z, k4.w};
    float kr[4];
    #pragma unroll
    for (int i = 0; i < 4; ++i) {
      float pk = __shfl_xor(kx[i], 16, 32);
      float r  = (lane < 16) ? -pk : pk;
      float sn, cs;
      __sincosf((float)pos_cur * invf[i], &sn, &cs);
      kr[i] = kx[i] * cs + r * sn;
    }

    // scores for 4 heads (q already scaled)
    float sc[GG];
    #pragma unroll
    for (int g = 0; g < GG; ++g)
      sc[g] = qr[g][0]*kr[0] + qr[g][1]*kr[1] + qr[g][2]*kr[2] + qr[g][3]*kr[3];
    #pragma unroll
    for (int off = 16; off > 0; off >>= 1) {
      #pragma unroll
      for (int g = 0; g < GG; ++g)
        sc[g] += __shfl_xor(sc[g], off, 32);
    }

    // online softmax + V accumulate
    float vx[4] = {v4.x, v4.y, v4.z, v4.w};
    #pragma unroll
    for (int g = 0; g < GG; ++g) {
      float mn   = fmaxf(m[g], sc[g]);
      float corr = __expf(m[g] - mn);
      float pw   = __expf(sc[g] - mn);
      l[g] = l[g] * corr + pw;
      #pragma unroll
      for (int i = 0; i < 4; ++i)
        acc[g][i] = acc[g][i] * corr + pw * vx[i];
      m[g] = mn;
    }

    k4 = nk4; v4 = nv4; pos_cur = pos_nxt;
  }

  // write partial state
  float* pb = part + ((size_t)bkv * PGROUPS + p) * PSTRIDE;
  #pragma unroll
  for (int g = 0; g < GG; ++g) {
    *(float4*)(pb + g * DD + d0) =
        make_float4(acc[g][0], acc[g][1], acc[g][2], acc[g][3]);
  }
  if (lane == 0) {
    #pragma unroll
    for (int g = 0; g < GG; ++g) {
      pb[GG * DD + g]      = m[g];
      pb[GG * DD + GG + g] = l[g];
    }
  }
}

// Kernel 2: combine the 64 partials per (b, h). grid = B*H, block = 128 (one d each).
__global__ __launch_bounds__(128) void pa_combine(
    const float* __restrict__ part, float* __restrict__ out)
{
  const int bh  = blockIdx.x;      // 0..511
  const int b   = bh >> 5;
  const int h   = bh & 31;
  const int kvh = h >> 2;
  const int g   = h & 3;
  const int d   = threadIdx.x;

  const float* pbase = part + ((size_t)(b * KVHH + kvh)) * PGROUPS * PSTRIDE;
  float M = -1e30f, L = 0.f, o = 0.f;
  for (int p = 0; p < PGROUPS; ++p) {
    const float* pp = pbase + (size_t)p * PSTRIDE;
    float mp = pp[GG * DD + g];
    float lp = pp[GG * DD + GG + g];
    float a  = pp[g * DD + d];
    float Mn = fmaxf(M, mp);
    float e0 = __expf(M - Mn);
    float e1 = __expf(mp - Mn);
    o = o * e0 + a * e1;
    L = L * e0 + lp * e1;
    M = Mn;
  }
  out[((size_t)b * HH + h) * DD + d] = o / L;
}

extern "C" void kernel_launch(void* const* d_in, const int* in_sizes, int n_in,
                              void* d_out, int out_size, void* d_ws, size_t ws_size,
                              hipStream_t stream) {
  const float* q_p   = (const float*)d_in[0];
  const float* kc_p  = (const float*)d_in[1];
  const float* vc_p  = (const float*)d_in[2];
  const int*   slots = (const int*)d_in[3];
  const int*   poss  = (const int*)d_in[4];
  const int*   ctxl  = (const int*)d_in[5];
  float* part = (float*)d_ws;   // needs B*KVH*PGROUPS*PSTRIDE*4 ≈ 17 MB
  float* outp = (float*)d_out;

  pa_split<<<BB * KVHH * (PGROUPS / 8), 256, 0, stream>>>(
      q_p, kc_p, vc_p, slots, poss, ctxl, part);
  pa_combine<<<BB * HH, 128, 0, stream>>>(part, outp);
}